// Round 1
// baseline (1337.172 us; speedup 1.0000x reference)
//
#include <hip/hip_runtime.h>

#define N_NODES 50000
#define N_EDGES 800000
#define NFEAT   512
#define NHID    256
#define NCLASS  64

// ---------------- GEMM1: h0 = x @ W1   (x:[N,512] fp32, W1:[512,256]) ----------------
// 8 rows per block, 256 threads; x rows staged in LDS, W1 row streamed (coalesced,
// L2-resident: 512KB). Each thread owns one output column, 8 accumulators.
__global__ __launch_bounds__(256) void gemm1_kernel(const float* __restrict__ x,
                                                    const float* __restrict__ W1,
                                                    float* __restrict__ h0) {
    __shared__ float xs[8][NFEAT];   // 16 KB
    const int row0 = blockIdx.x * 8;
    const int tid  = threadIdx.x;

    const float4* x4  = (const float4*)(x + (size_t)row0 * NFEAT);
    float4*       xs4 = (float4*)&xs[0][0];
    #pragma unroll
    for (int i = 0; i < (8 * NFEAT / 4) / 256; ++i)
        xs4[tid + i * 256] = x4[tid + i * 256];
    __syncthreads();

    const int c = tid;
    float acc[8] = {0.f,0.f,0.f,0.f,0.f,0.f,0.f,0.f};
    for (int k = 0; k < NFEAT; ++k) {
        float wv = W1[k * NHID + c];
        #pragma unroll
        for (int r = 0; r < 8; ++r) acc[r] += xs[r][k] * wv;  // xs[r][k] broadcast (conflict-free)
    }
    #pragma unroll
    for (int r = 0; r < 8; ++r)
        h0[(size_t)(row0 + r) * NHID + c] = acc[r];
}

// ---------------- SpMM1: agg0[dst] += w * h0[src]  (d = 256) ----------------
// One block per edge; thread t handles feature t. Gather is one coalesced 1KB row read;
// scatter is 256 fp32 global atomics (device scope by default).
__global__ __launch_bounds__(256) void spmm1_kernel(const int* __restrict__ src,
                                                    const int* __restrict__ dst,
                                                    const float* __restrict__ w,
                                                    const float* __restrict__ h0,
                                                    float* __restrict__ agg0) {
    const int e = blockIdx.x;
    const int t = threadIdx.x;
    const int s = src[e];
    const int d = dst[e];
    const float wt = w[e];
    float val = h0[(size_t)s * NHID + t] * wt;
    atomicAdd(&agg0[(size_t)d * NHID + t], val);
}

// ---------------- GEMM2: h2 = relu(agg0 + b1) @ W2   ([N,256]@[256,64]) ----------------
// 16 rows per block; ReLU+bias fused into the LDS staging load. Thread layout:
// c = tid&63 (output col), rg = tid>>6 selects a group of 4 rows.
__global__ __launch_bounds__(256) void gemm2_kernel(const float* __restrict__ agg0,
                                                    const float* __restrict__ b1,
                                                    const float* __restrict__ W2,
                                                    float* __restrict__ h2) {
    __shared__ float hs[16][NHID];   // 16 KB
    const int row0 = blockIdx.x * 16;
    const int tid  = threadIdx.x;

    float* hsf = &hs[0][0];
    #pragma unroll
    for (int i = 0; i < (16 * NHID) / 256; ++i) {
        int idx = tid + i * 256;
        int col = idx & (NHID - 1);
        float v = agg0[(size_t)row0 * NHID + idx] + b1[col];
        hsf[idx] = v > 0.f ? v : 0.f;
    }
    __syncthreads();

    const int c  = tid & 63;
    const int rg = tid >> 6;   // 0..3 -> rows rg*4 .. rg*4+3
    float acc[4] = {0.f,0.f,0.f,0.f};
    for (int k = 0; k < NHID; ++k) {
        float wv = W2[k * NCLASS + c];
        #pragma unroll
        for (int r = 0; r < 4; ++r) acc[r] += hs[rg * 4 + r][k] * wv;
    }
    #pragma unroll
    for (int r = 0; r < 4; ++r)
        h2[(size_t)(row0 + rg * 4 + r) * NCLASS + c] = acc[r];
}

// ---------------- SpMM2: agg1[dst] += w * h2[src]  (d = 64) ----------------
// 4 edges per block (one wave each); lane = feature.
__global__ __launch_bounds__(256) void spmm2_kernel(const int* __restrict__ src,
                                                    const int* __restrict__ dst,
                                                    const float* __restrict__ w,
                                                    const float* __restrict__ h2,
                                                    float* __restrict__ agg1) {
    const int lane = threadIdx.x & 63;
    const int e    = blockIdx.x * 4 + (threadIdx.x >> 6);
    const int s = src[e];
    const int d = dst[e];
    float val = h2[(size_t)s * NCLASS + lane] * w[e];
    atomicAdd(&agg1[(size_t)d * NCLASS + lane], val);
}

// ---------------- log_softmax over 64 classes, + b2 ----------------
// One wave (64 lanes) per row; shuffle-reduce max and sum across the wave.
__global__ __launch_bounds__(256) void logsoftmax_kernel(const float* __restrict__ agg1,
                                                         const float* __restrict__ b2,
                                                         float* __restrict__ out) {
    const int lane = threadIdx.x & 63;
    const int row  = blockIdx.x * 4 + (threadIdx.x >> 6);
    float v = agg1[(size_t)row * NCLASS + lane] + b2[lane];

    float m = v;
    #pragma unroll
    for (int off = 32; off > 0; off >>= 1) m = fmaxf(m, __shfl_xor(m, off, 64));
    float ex = expf(v - m);
    float s = ex;
    #pragma unroll
    for (int off = 32; off > 0; off >>= 1) s += __shfl_xor(s, off, 64);

    out[(size_t)row * NCLASS + lane] = v - m - logf(s);
}

extern "C" void kernel_launch(void* const* d_in, const int* in_sizes, int n_in,
                              void* d_out, int out_size, void* d_ws, size_t ws_size,
                              hipStream_t stream) {
    const float* x   = (const float*)d_in[0];
    const int*   es0 = (const int*)  d_in[1];
    const int*   ed0 = (const int*)  d_in[2];
    const float* ew0 = (const float*)d_in[3];
    const int*   es1 = (const int*)  d_in[4];
    const int*   ed1 = (const int*)  d_in[5];
    const float* ew1 = (const float*)d_in[6];
    const float* W1  = (const float*)d_in[7];
    const float* b1  = (const float*)d_in[8];
    const float* W2  = (const float*)d_in[9];
    const float* b2  = (const float*)d_in[10];
    float* out = (float*)d_out;

    // Workspace layout (102.4 MB total, region A reused after SpMM1 consumes h0):
    //   A [0, 51.2MB):   h0 [50000x256 f32]; later h2 [0,12.8MB) + agg1 [12.8,25.6MB)
    //   B [51.2, 102.4): agg0 [50000x256 f32]
    char* ws = (char*)d_ws;
    const size_t SZ_A = (size_t)N_NODES * NHID * sizeof(float);   // 51,200,000
    float* h0   = (float*)ws;
    float* agg0 = (float*)(ws + SZ_A);
    float* h2   = (float*)ws;
    float* agg1 = (float*)(ws + (size_t)N_NODES * NCLASS * sizeof(float));

    hipMemsetAsync(agg0, 0, SZ_A, stream);
    gemm1_kernel<<<N_NODES / 8, 256, 0, stream>>>(x, W1, h0);
    spmm1_kernel<<<N_EDGES, 256, 0, stream>>>(es0, ed0, ew0, h0, agg0);
    gemm2_kernel<<<N_NODES / 16, 256, 0, stream>>>(agg0, b1, W2, h2);
    // agg1 overlaps the (now dead) h0 region — zero it only after GEMM2 ran.
    hipMemsetAsync(agg1, 0, (size_t)N_NODES * NCLASS * sizeof(float), stream);
    spmm2_kernel<<<N_EDGES / 4, 256, 0, stream>>>(es1, ed1, ew1, h2, agg1);
    logsoftmax_kernel<<<N_NODES / 4, 256, 0, stream>>>(agg1, b2, out);
}

// Round 2
// 836.414 us; speedup vs baseline: 1.5987x; 1.5987x over previous
//
#include <hip/hip_runtime.h>

#define N_NODES 50000
#define N_EDGES 800000
#define NFEAT   512
#define NHID    256
#define NCLASS  64

#define EDGE_BLOCKS ((N_EDGES + 255) / 256)   // 3125
#define NODE_BLOCKS ((N_NODES + 255) / 256)   // 196

// ---------------- GEMM1: h0 = x @ W1   (x:[N,512] fp32, W1:[512,256]) ----------------
__global__ __launch_bounds__(256) void gemm1_kernel(const float* __restrict__ x,
                                                    const float* __restrict__ W1,
                                                    float* __restrict__ h0) {
    __shared__ float xs[8][NFEAT];   // 16 KB
    const int row0 = blockIdx.x * 8;
    const int tid  = threadIdx.x;

    const float4* x4  = (const float4*)(x + (size_t)row0 * NFEAT);
    float4*       xs4 = (float4*)&xs[0][0];
    #pragma unroll
    for (int i = 0; i < (8 * NFEAT / 4) / 256; ++i)
        xs4[tid + i * 256] = x4[tid + i * 256];
    __syncthreads();

    const int c = tid;
    float acc[8] = {0.f,0.f,0.f,0.f,0.f,0.f,0.f,0.f};
    for (int k = 0; k < NFEAT; ++k) {
        float wv = W1[k * NHID + c];
        #pragma unroll
        for (int r = 0; r < 8; ++r) acc[r] += xs[r][k] * wv;
    }
    #pragma unroll
    for (int r = 0; r < 8; ++r)
        h0[(size_t)(row0 + r) * NHID + c] = acc[r];
}

// ---------------- CSR build: histogram -> scan -> scatter ----------------
__global__ __launch_bounds__(256) void hist_kernel(const int* __restrict__ dst,
                                                   int* __restrict__ deg) {
    int e = blockIdx.x * 256 + threadIdx.x;
    if (e < N_EDGES) atomicAdd(&deg[dst[e]], 1);
}

__global__ __launch_bounds__(256) void scan_partial_kernel(const int* __restrict__ deg,
                                                           int* __restrict__ partial) {
    __shared__ int s[256];
    int i = blockIdx.x * 256 + threadIdx.x;
    int t = threadIdx.x;
    s[t] = (i < N_NODES) ? deg[i] : 0;
    __syncthreads();
    for (int off = 128; off > 0; off >>= 1) {
        if (t < off) s[t] += s[t + off];
        __syncthreads();
    }
    if (t == 0) partial[blockIdx.x] = s[0];
}

// single block: exclusive scan of NODE_BLOCKS partials (in place)
__global__ __launch_bounds__(256) void scan_top_kernel(int* __restrict__ partial) {
    __shared__ int s[256];
    int t = threadIdx.x;
    int v = (t < NODE_BLOCKS) ? partial[t] : 0;
    s[t] = v;
    __syncthreads();
    for (int off = 1; off < 256; off <<= 1) {
        int a = (t >= off) ? s[t - off] : 0;
        __syncthreads();
        s[t] += a;
        __syncthreads();
    }
    if (t < NODE_BLOCKS) partial[t] = s[t] - v;   // exclusive
}

__global__ __launch_bounds__(256) void scan_final_kernel(const int* __restrict__ deg,
                                                         const int* __restrict__ partial,
                                                         int* __restrict__ base,
                                                         int* __restrict__ cursor) {
    __shared__ int s[256];
    int i = blockIdx.x * 256 + threadIdx.x;
    int t = threadIdx.x;
    int v = (i < N_NODES) ? deg[i] : 0;
    s[t] = v;
    __syncthreads();
    for (int off = 1; off < 256; off <<= 1) {
        int a = (t >= off) ? s[t - off] : 0;
        __syncthreads();
        s[t] += a;
        __syncthreads();
    }
    int excl = s[t] - v + partial[blockIdx.x];
    if (i < N_NODES) { base[i] = excl; cursor[i] = excl; }
}

__global__ __launch_bounds__(256) void scatter_kernel(const int* __restrict__ src,
                                                      const int* __restrict__ dst,
                                                      const float* __restrict__ w,
                                                      int* __restrict__ cursor,
                                                      int* __restrict__ src_s,
                                                      float* __restrict__ w_s) {
    int e = blockIdx.x * 256 + threadIdx.x;
    if (e < N_EDGES) {
        int p = atomicAdd(&cursor[dst[e]], 1);
        src_s[p] = src[e];
        w_s[p]   = w[e];
    }
}

// ---------------- SpMM1 pull: agg0[i] = sum_j w_s[p] * h0[src_s[p]]  (d=256) ----------
// One wave per node, float4 per lane (64 lanes x 16B = 1KB row). 4 nodes/block.
__global__ __launch_bounds__(256) void spmm1_pull_kernel(const int* __restrict__ base,
                                                         const int* __restrict__ deg,
                                                         const int* __restrict__ src_s,
                                                         const float* __restrict__ w_s,
                                                         const float* __restrict__ h0,
                                                         float* __restrict__ agg0) {
    const int node = blockIdx.x * 4 + (threadIdx.x >> 6);
    const int lane = threadIdx.x & 63;
    const int start = base[node];
    const int len   = deg[node];
    const float4* h4 = (const float4*)h0;
    float4 acc = {0.f, 0.f, 0.f, 0.f};
    for (int j = 0; j < len; ++j) {
        int p = start + j;
        int s = src_s[p];
        float wt = w_s[p];
        float4 hv = h4[(size_t)s * 64 + lane];
        acc.x += wt * hv.x; acc.y += wt * hv.y;
        acc.z += wt * hv.z; acc.w += wt * hv.w;
    }
    ((float4*)agg0)[(size_t)node * 64 + lane] = acc;
}

// ---------------- GEMM2: h2 = relu(agg0 + b1) @ W2   ([N,256]@[256,64]) ----------------
__global__ __launch_bounds__(256) void gemm2_kernel(const float* __restrict__ agg0,
                                                    const float* __restrict__ b1,
                                                    const float* __restrict__ W2,
                                                    float* __restrict__ h2) {
    __shared__ float hs[16][NHID];   // 16 KB
    const int row0 = blockIdx.x * 16;
    const int tid  = threadIdx.x;

    float* hsf = &hs[0][0];
    #pragma unroll
    for (int i = 0; i < (16 * NHID) / 256; ++i) {
        int idx = tid + i * 256;
        int col = idx & (NHID - 1);
        float v = agg0[(size_t)row0 * NHID + idx] + b1[col];
        hsf[idx] = v > 0.f ? v : 0.f;
    }
    __syncthreads();

    const int c  = tid & 63;
    const int rg = tid >> 6;
    float acc[4] = {0.f,0.f,0.f,0.f};
    for (int k = 0; k < NHID; ++k) {
        float wv = W2[k * NCLASS + c];
        #pragma unroll
        for (int r = 0; r < 4; ++r) acc[r] += hs[rg * 4 + r][k] * wv;
    }
    #pragma unroll
    for (int r = 0; r < 4; ++r)
        h2[(size_t)(row0 + rg * 4 + r) * NCLASS + c] = acc[r];
}

// ---------------- SpMM2 pull: agg1[i] = sum w * h2[src]  (d=64) ----------------
__global__ __launch_bounds__(256) void spmm2_pull_kernel(const int* __restrict__ base,
                                                         const int* __restrict__ deg,
                                                         const int* __restrict__ src_s,
                                                         const float* __restrict__ w_s,
                                                         const float* __restrict__ h2,
                                                         float* __restrict__ agg1) {
    const int node = blockIdx.x * 4 + (threadIdx.x >> 6);
    const int lane = threadIdx.x & 63;
    const int start = base[node];
    const int len   = deg[node];
    float acc = 0.f;
    for (int j = 0; j < len; ++j) {
        int p = start + j;
        int s = src_s[p];
        float wt = w_s[p];
        acc += wt * h2[(size_t)s * NCLASS + lane];
    }
    agg1[(size_t)node * NCLASS + lane] = acc;
}

// ---------------- log_softmax over 64 classes, + b2 ----------------
__global__ __launch_bounds__(256) void logsoftmax_kernel(const float* __restrict__ agg1,
                                                         const float* __restrict__ b2,
                                                         float* __restrict__ out) {
    const int lane = threadIdx.x & 63;
    const int row  = blockIdx.x * 4 + (threadIdx.x >> 6);
    float v = agg1[(size_t)row * NCLASS + lane] + b2[lane];

    float m = v;
    #pragma unroll
    for (int off = 32; off > 0; off >>= 1) m = fmaxf(m, __shfl_xor(m, off, 64));
    float ex = expf(v - m);
    float s = ex;
    #pragma unroll
    for (int off = 32; off > 0; off >>= 1) s += __shfl_xor(s, off, 64);

    out[(size_t)row * NCLASS + lane] = v - m - logf(s);
}

extern "C" void kernel_launch(void* const* d_in, const int* in_sizes, int n_in,
                              void* d_out, int out_size, void* d_ws, size_t ws_size,
                              hipStream_t stream) {
    const float* x   = (const float*)d_in[0];
    const int*   es0 = (const int*)  d_in[1];
    const int*   ed0 = (const int*)  d_in[2];
    const float* ew0 = (const float*)d_in[3];
    const int*   es1 = (const int*)  d_in[4];
    const int*   ed1 = (const int*)  d_in[5];
    const float* ew1 = (const float*)d_in[6];
    const float* W1  = (const float*)d_in[7];
    const float* b1  = (const float*)d_in[8];
    const float* W2  = (const float*)d_in[9];
    const float* b2  = (const float*)d_in[10];
    float* out = (float*)d_out;

    // ws layout (102.4 MB):
    //   A [0, 51.2MB):   h0 [50000x256]; after spmm1: h2 [0,12.8) + agg1 [12.8,25.6)
    //   B [51.2,102.4):  agg0 [50000x256]
    char* ws = (char*)d_ws;
    const size_t SZ_A = (size_t)N_NODES * NHID * sizeof(float);
    float* h0   = (float*)ws;
    float* agg0 = (float*)(ws + SZ_A);
    float* h2   = (float*)ws;
    float* agg1 = (float*)(ws + (size_t)N_NODES * NCLASS * sizeof(float));

    // CSR scratch lives in d_out (12.8 MB; dead until logsoftmax overwrites all of it).
    // deg/base/cursor: 50000 ints each; partial: 1024 ints; src_s/w_s: 800000 each.
    int*   deg     = (int*)d_out;
    int*   basep   = deg + N_NODES;
    int*   cursor  = basep + N_NODES;
    int*   partial = cursor + N_NODES;
    int*   src_s   = partial + 1024;
    float* w_s     = (float*)(src_s + N_EDGES);
    // end offset = (3*50000 + 1024 + 2*800000)*4 B = 7.0 MB < 12.8 MB

    // ---- build CSR for layer-1 edges (by dst) ----
    hipMemsetAsync(deg, 0, N_NODES * sizeof(int), stream);
    hist_kernel<<<EDGE_BLOCKS, 256, 0, stream>>>(ed0, deg);
    scan_partial_kernel<<<NODE_BLOCKS, 256, 0, stream>>>(deg, partial);
    scan_top_kernel<<<1, 256, 0, stream>>>(partial);
    scan_final_kernel<<<NODE_BLOCKS, 256, 0, stream>>>(deg, partial, basep, cursor);
    scatter_kernel<<<EDGE_BLOCKS, 256, 0, stream>>>(es0, ed0, ew0, cursor, src_s, w_s);

    gemm1_kernel<<<N_NODES / 8, 256, 0, stream>>>(x, W1, h0);
    spmm1_pull_kernel<<<N_NODES / 4, 256, 0, stream>>>(basep, deg, src_s, w_s, h0, agg0);

    // ---- build CSR for layer-2 edges (reuse same scratch) ----
    hipMemsetAsync(deg, 0, N_NODES * sizeof(int), stream);
    hist_kernel<<<EDGE_BLOCKS, 256, 0, stream>>>(ed1, deg);
    scan_partial_kernel<<<NODE_BLOCKS, 256, 0, stream>>>(deg, partial);
    scan_top_kernel<<<1, 256, 0, stream>>>(partial);
    scan_final_kernel<<<NODE_BLOCKS, 256, 0, stream>>>(deg, partial, basep, cursor);
    scatter_kernel<<<EDGE_BLOCKS, 256, 0, stream>>>(es1, ed1, ew1, cursor, src_s, w_s);

    gemm2_kernel<<<N_NODES / 16, 256, 0, stream>>>(agg0, b1, W2, h2);
    spmm2_pull_kernel<<<N_NODES / 4, 256, 0, stream>>>(basep, deg, src_s, w_s, h2, agg1);
    logsoftmax_kernel<<<N_NODES / 4, 256, 0, stream>>>(agg1, b2, out);
}

// Round 3
// 731.767 us; speedup vs baseline: 1.8273x; 1.1430x over previous
//
#include <hip/hip_runtime.h>

#define N_NODES 50000
#define N_EDGES 800000
#define NFEAT   512
#define NHID    256
#define NCLASS  64

#define EDGE_BLOCKS ((N_EDGES + 255) / 256)   // 3125
#define NODE_BLOCKS ((N_NODES + 255) / 256)   // 196

typedef short short8 __attribute__((ext_vector_type(8)));
typedef float floatx4 __attribute__((ext_vector_type(4)));

__device__ inline short f2bf(float f) {
    unsigned u = __builtin_bit_cast(unsigned, f);
    u += 0x7FFF + ((u >> 16) & 1);   // round-to-nearest-even
    return (short)(u >> 16);
}

// ---------------- cast x (fp32 [50000x512]) -> xb (bf16) ----------------
__global__ __launch_bounds__(256) void cast_x_kernel(const float* __restrict__ x,
                                                     short* __restrict__ xb) {
    const int i = (blockIdx.x * 256 + threadIdx.x) * 8;   // 12500 blocks covers 25.6M
    float4 a = ((const float4*)(x + i))[0];
    float4 b = ((const float4*)(x + i))[1];
    short8 o;
    o[0] = f2bf(a.x); o[1] = f2bf(a.y); o[2] = f2bf(a.z); o[3] = f2bf(a.w);
    o[4] = f2bf(b.x); o[5] = f2bf(b.y); o[6] = f2bf(b.z); o[7] = f2bf(b.w);
    *(short8*)(xb + i) = o;
}

// ---------------- cast + transpose W1 (fp32 [512x256]) -> Wt (bf16 [256x512]) --------
__global__ __launch_bounds__(256) void cast_w1t_kernel(const float* __restrict__ W1,
                                                       short* __restrict__ Wt) {
    const int k = blockIdx.x;      // 512
    const int n = threadIdx.x;     // 256
    Wt[n * NFEAT + k] = f2bf(W1[k * NHID + n]);
}

// ---------------- GEMM1 (MFMA): h0 = xb @ Wt^T   ([50000x512]bf16 @ [512x256]) -------
// One block per 16-row M-tile (3125 blocks, exact). 4 waves cover N=256; each wave
// computes a 16x64 strip: 4 accumulators, K-loop 16 x mfma_f32_16x16x32_bf16.
// Layouts (m89-verified): A[m=lane&15][k=quad*8+j]; B(=W1^T rows)[n=lane&15][k=quad*8+j];
// C/D col=lane&15, row=quad*4+reg.
__global__ __launch_bounds__(256) void gemm1_mfma_kernel(const short* __restrict__ xb,
                                                         const short* __restrict__ Wt,
                                                         float* __restrict__ h0) {
    const int wave = threadIdx.x >> 6;        // 0..3
    const int lane = threadIdx.x & 63;
    const int m    = lane & 15;
    const int q    = lane >> 4;               // quad 0..3
    const int row0 = blockIdx.x * 16;
    const int n0   = wave * 64;

    const short* arow = xb + (size_t)(row0 + m) * NFEAT + q * 8;
    const short* brow = Wt + (size_t)(n0 + m) * NFEAT + q * 8;

    floatx4 acc0 = {0.f,0.f,0.f,0.f}, acc1 = {0.f,0.f,0.f,0.f};
    floatx4 acc2 = {0.f,0.f,0.f,0.f}, acc3 = {0.f,0.f,0.f,0.f};

    for (int k0 = 0; k0 < NFEAT; k0 += 32) {
        short8 a = *(const short8*)(arow + k0);
        short8 b0 = *(const short8*)(brow + k0);
        short8 b1 = *(const short8*)(brow + 16 * NFEAT + k0);
        short8 b2 = *(const short8*)(brow + 32 * NFEAT + k0);
        short8 b3 = *(const short8*)(brow + 48 * NFEAT + k0);
        acc0 = __builtin_amdgcn_mfma_f32_16x16x32_bf16(a, b0, acc0, 0, 0, 0);
        acc1 = __builtin_amdgcn_mfma_f32_16x16x32_bf16(a, b1, acc1, 0, 0, 0);
        acc2 = __builtin_amdgcn_mfma_f32_16x16x32_bf16(a, b2, acc2, 0, 0, 0);
        acc3 = __builtin_amdgcn_mfma_f32_16x16x32_bf16(a, b3, acc3, 0, 0, 0);
    }

    const int row = row0 + q * 4;
    #pragma unroll
    for (int r = 0; r < 4; ++r) {
        h0[(size_t)(row + r) * NHID + n0 +  0 + m] = acc0[r];
        h0[(size_t)(row + r) * NHID + n0 + 16 + m] = acc1[r];
        h0[(size_t)(row + r) * NHID + n0 + 32 + m] = acc2[r];
        h0[(size_t)(row + r) * NHID + n0 + 48 + m] = acc3[r];
    }
}

// ---------------- CSR build: histogram -> scan -> scatter ----------------
__global__ __launch_bounds__(256) void hist_kernel(const int* __restrict__ dst,
                                                   int* __restrict__ deg) {
    int e = blockIdx.x * 256 + threadIdx.x;
    if (e < N_EDGES) atomicAdd(&deg[dst[e]], 1);
}

__global__ __launch_bounds__(256) void scan_partial_kernel(const int* __restrict__ deg,
                                                           int* __restrict__ partial) {
    __shared__ int s[256];
    int i = blockIdx.x * 256 + threadIdx.x;
    int t = threadIdx.x;
    s[t] = (i < N_NODES) ? deg[i] : 0;
    __syncthreads();
    for (int off = 128; off > 0; off >>= 1) {
        if (t < off) s[t] += s[t + off];
        __syncthreads();
    }
    if (t == 0) partial[blockIdx.x] = s[0];
}

__global__ __launch_bounds__(256) void scan_top_kernel(int* __restrict__ partial) {
    __shared__ int s[256];
    int t = threadIdx.x;
    int v = (t < NODE_BLOCKS) ? partial[t] : 0;
    s[t] = v;
    __syncthreads();
    for (int off = 1; off < 256; off <<= 1) {
        int a = (t >= off) ? s[t - off] : 0;
        __syncthreads();
        s[t] += a;
        __syncthreads();
    }
    if (t < NODE_BLOCKS) partial[t] = s[t] - v;   // exclusive
}

__global__ __launch_bounds__(256) void scan_final_kernel(const int* __restrict__ deg,
                                                         const int* __restrict__ partial,
                                                         int* __restrict__ base,
                                                         int* __restrict__ cursor) {
    __shared__ int s[256];
    int i = blockIdx.x * 256 + threadIdx.x;
    int t = threadIdx.x;
    int v = (i < N_NODES) ? deg[i] : 0;
    s[t] = v;
    __syncthreads();
    for (int off = 1; off < 256; off <<= 1) {
        int a = (t >= off) ? s[t - off] : 0;
        __syncthreads();
        s[t] += a;
        __syncthreads();
    }
    int excl = s[t] - v + partial[blockIdx.x];
    if (i < N_NODES) { base[i] = excl; cursor[i] = excl; }
}

__global__ __launch_bounds__(256) void scatter_kernel(const int* __restrict__ src,
                                                      const int* __restrict__ dst,
                                                      const float* __restrict__ w,
                                                      int* __restrict__ cursor,
                                                      int* __restrict__ src_s,
                                                      float* __restrict__ w_s) {
    int e = blockIdx.x * 256 + threadIdx.x;
    if (e < N_EDGES) {
        int p = atomicAdd(&cursor[dst[e]], 1);
        src_s[p] = src[e];
        w_s[p]   = w[e];
    }
}

// ---------------- SpMM1 pull: agg0[i] = sum_j w_s[p] * h0[src_s[p]]  (d=256) ----------
__global__ __launch_bounds__(256) void spmm1_pull_kernel(const int* __restrict__ base,
                                                         const int* __restrict__ deg,
                                                         const int* __restrict__ src_s,
                                                         const float* __restrict__ w_s,
                                                         const float* __restrict__ h0,
                                                         float* __restrict__ agg0) {
    const int node = blockIdx.x * 4 + (threadIdx.x >> 6);
    const int lane = threadIdx.x & 63;
    const int start = base[node];
    const int len   = deg[node];
    const float4* h4 = (const float4*)h0;
    float4 acc = {0.f, 0.f, 0.f, 0.f};
    for (int j = 0; j < len; ++j) {
        int p = start + j;
        int s = src_s[p];
        float wt = w_s[p];
        float4 hv = h4[(size_t)s * 64 + lane];
        acc.x += wt * hv.x; acc.y += wt * hv.y;
        acc.z += wt * hv.z; acc.w += wt * hv.w;
    }
    ((float4*)agg0)[(size_t)node * 64 + lane] = acc;
}

// ---------------- GEMM2: h2 = relu(agg0 + b1) @ W2   ([N,256]@[256,64]) ----------------
__global__ __launch_bounds__(256) void gemm2_kernel(const float* __restrict__ agg0,
                                                    const float* __restrict__ b1,
                                                    const float* __restrict__ W2,
                                                    float* __restrict__ h2) {
    __shared__ float hs[16][NHID];   // 16 KB
    const int row0 = blockIdx.x * 16;
    const int tid  = threadIdx.x;

    float* hsf = &hs[0][0];
    #pragma unroll
    for (int i = 0; i < (16 * NHID) / 256; ++i) {
        int idx = tid + i * 256;
        int col = idx & (NHID - 1);
        float v = agg0[(size_t)row0 * NHID + idx] + b1[col];
        hsf[idx] = v > 0.f ? v : 0.f;
    }
    __syncthreads();

    const int c  = tid & 63;
    const int rg = tid >> 6;
    float acc[4] = {0.f,0.f,0.f,0.f};
    for (int k = 0; k < NHID; ++k) {
        float wv = W2[k * NCLASS + c];
        #pragma unroll
        for (int r = 0; r < 4; ++r) acc[r] += hs[rg * 4 + r][k] * wv;
    }
    #pragma unroll
    for (int r = 0; r < 4; ++r)
        h2[(size_t)(row0 + rg * 4 + r) * NCLASS + c] = acc[r];
}

// ---------------- SpMM2 pull: agg1[i] = sum w * h2[src]  (d=64) ----------------
__global__ __launch_bounds__(256) void spmm2_pull_kernel(const int* __restrict__ base,
                                                         const int* __restrict__ deg,
                                                         const int* __restrict__ src_s,
                                                         const float* __restrict__ w_s,
                                                         const float* __restrict__ h2,
                                                         float* __restrict__ agg1) {
    const int node = blockIdx.x * 4 + (threadIdx.x >> 6);
    const int lane = threadIdx.x & 63;
    const int start = base[node];
    const int len   = deg[node];
    float acc = 0.f;
    for (int j = 0; j < len; ++j) {
        int p = start + j;
        int s = src_s[p];
        float wt = w_s[p];
        acc += wt * h2[(size_t)s * NCLASS + lane];
    }
    agg1[(size_t)node * NCLASS + lane] = acc;
}

// ---------------- log_softmax over 64 classes, + b2 ----------------
__global__ __launch_bounds__(256) void logsoftmax_kernel(const float* __restrict__ agg1,
                                                         const float* __restrict__ b2,
                                                         float* __restrict__ out) {
    const int lane = threadIdx.x & 63;
    const int row  = blockIdx.x * 4 + (threadIdx.x >> 6);
    float v = agg1[(size_t)row * NCLASS + lane] + b2[lane];

    float m = v;
    #pragma unroll
    for (int off = 32; off > 0; off >>= 1) m = fmaxf(m, __shfl_xor(m, off, 64));
    float ex = expf(v - m);
    float s = ex;
    #pragma unroll
    for (int off = 32; off > 0; off >>= 1) s += __shfl_xor(s, off, 64);

    out[(size_t)row * NCLASS + lane] = v - m - logf(s);
}

extern "C" void kernel_launch(void* const* d_in, const int* in_sizes, int n_in,
                              void* d_out, int out_size, void* d_ws, size_t ws_size,
                              hipStream_t stream) {
    const float* x   = (const float*)d_in[0];
    const int*   es0 = (const int*)  d_in[1];
    const int*   ed0 = (const int*)  d_in[2];
    const float* ew0 = (const float*)d_in[3];
    const int*   es1 = (const int*)  d_in[4];
    const int*   ed1 = (const int*)  d_in[5];
    const float* ew1 = (const float*)d_in[6];
    const float* W1  = (const float*)d_in[7];
    const float* b1  = (const float*)d_in[8];
    const float* W2  = (const float*)d_in[9];
    const float* b2  = (const float*)d_in[10];
    float* out = (float*)d_out;

    // ws layout (102.4 MB):
    //   A [0, 51.2MB):   h0 [50000x256 f32]; after spmm1: h2 [0,12.8) + agg1 [12.8,25.6)
    //   B [51.2,102.4):  xb (bf16 x, 51.2MB) during gemm1; then agg0 [50000x256 f32]
    //   (xb is dead once gemm1_mfma finishes; spmm1 overwrites the region with agg0)
    char* ws = (char*)d_ws;
    const size_t SZ_A = (size_t)N_NODES * NHID * sizeof(float);
    float* h0   = (float*)ws;
    short* xb   = (short*)(ws + SZ_A);
    float* agg0 = (float*)(ws + SZ_A);
    float* h2   = (float*)ws;
    float* agg1 = (float*)(ws + (size_t)N_NODES * NCLASS * sizeof(float));

    // d_out scratch (12.8 MB total; fully overwritten by logsoftmax at the end):
    //   [0, 7.0MB):  CSR build arrays;  [8MB, 8.25MB): Wt (bf16 W1^T)
    int*   deg     = (int*)d_out;
    int*   basep   = deg + N_NODES;
    int*   cursor  = basep + N_NODES;
    int*   partial = cursor + N_NODES;
    int*   src_s   = partial + 1024;
    float* w_s     = (float*)(src_s + N_EDGES);
    short* Wt      = (short*)((char*)d_out + (8u << 20));

    // ---- build CSR for layer-1 edges (by dst) ----
    hipMemsetAsync(deg, 0, N_NODES * sizeof(int), stream);
    hist_kernel<<<EDGE_BLOCKS, 256, 0, stream>>>(ed0, deg);
    scan_partial_kernel<<<NODE_BLOCKS, 256, 0, stream>>>(deg, partial);
    scan_top_kernel<<<1, 256, 0, stream>>>(partial);
    scan_final_kernel<<<NODE_BLOCKS, 256, 0, stream>>>(deg, partial, basep, cursor);
    scatter_kernel<<<EDGE_BLOCKS, 256, 0, stream>>>(es0, ed0, ew0, cursor, src_s, w_s);

    // ---- GEMM1 via bf16 MFMA ----
    cast_x_kernel<<<(N_NODES * NFEAT / 8) / 256, 256, 0, stream>>>(x, xb);
    cast_w1t_kernel<<<NFEAT, 256, 0, stream>>>(W1, Wt);
    gemm1_mfma_kernel<<<N_NODES / 16, 256, 0, stream>>>(xb, Wt, h0);

    spmm1_pull_kernel<<<N_NODES / 4, 256, 0, stream>>>(basep, deg, src_s, w_s, h0, agg0);

    // ---- build CSR for layer-2 edges (reuse same scratch) ----
    hipMemsetAsync(deg, 0, N_NODES * sizeof(int), stream);
    hist_kernel<<<EDGE_BLOCKS, 256, 0, stream>>>(ed1, deg);
    scan_partial_kernel<<<NODE_BLOCKS, 256, 0, stream>>>(deg, partial);
    scan_top_kernel<<<1, 256, 0, stream>>>(partial);
    scan_final_kernel<<<NODE_BLOCKS, 256, 0, stream>>>(deg, partial, basep, cursor);
    scatter_kernel<<<EDGE_BLOCKS, 256, 0, stream>>>(es1, ed1, ew1, cursor, src_s, w_s);

    gemm2_kernel<<<N_NODES / 16, 256, 0, stream>>>(agg0, b1, W2, h2);
    spmm2_pull_kernel<<<N_NODES / 4, 256, 0, stream>>>(basep, deg, src_s, w_s, h2, agg1);
    logsoftmax_kernel<<<N_NODES / 4, 256, 0, stream>>>(agg1, b2, out);
}

// Round 4
// 549.713 us; speedup vs baseline: 2.4325x; 1.3312x over previous
//
#include <hip/hip_runtime.h>

#define N_NODES 50000
#define N_EDGES 800000
#define NFEAT   512
#define NHID    256
#define NCLASS  64

#define EDGE_BLOCKS ((N_EDGES + 255) / 256)   // 3125
#define NODE_BLOCKS ((N_NODES + 255) / 256)   // 196
#define MTILES     ((N_NODES + 63) / 64)      // 782

typedef short short8  __attribute__((ext_vector_type(8)));
typedef short short4v __attribute__((ext_vector_type(4)));
typedef short short2v __attribute__((ext_vector_type(2)));
typedef float floatx4 __attribute__((ext_vector_type(4)));

__device__ inline short f2bf(float f) {
    unsigned u = __builtin_bit_cast(unsigned, f);
    u += 0x7FFF + ((u >> 16) & 1);   // round-to-nearest-even
    return (short)(u >> 16);
}
__device__ inline float bf2f(short v) {
    unsigned u = ((unsigned)(unsigned short)v) << 16;
    return __builtin_bit_cast(float, u);
}

// ---------------- cast+transpose W1 (fp32 [512x256]) -> Wt (bf16 [256x512]) ----------
__global__ __launch_bounds__(256) void cast_w1t_kernel(const float* __restrict__ W1,
                                                       short* __restrict__ Wt) {
    const int k = blockIdx.x;      // 512
    const int n = threadIdx.x;     // 256
    Wt[n * NFEAT + k] = f2bf(W1[k * NHID + n]);
}

// ---------------- cast+transpose W2 (fp32 [256x64]) -> W2t (bf16 [64x256]) -----------
__global__ __launch_bounds__(256) void cast_w2t_kernel(const float* __restrict__ W2,
                                                       short* __restrict__ W2t) {
    const int n = blockIdx.x;      // 64
    const int k = threadIdx.x;     // 256
    W2t[n * NHID + k] = f2bf(W2[k * NCLASS + n]);
}

// ---------------- GEMM1 (LDS-tiled MFMA, fused fp32->bf16 A-cast) --------------------
// Tile 64(M) x 256(N=full), BK=32, K=512 -> 16 chunks. 4 waves; wave w covers cols
// w*64..w*64+63 as 4x4 16x16x32 mfma tiles. h0 written as bf16.
__global__ __launch_bounds__(256) void gemm1_mfma_kernel(const float* __restrict__ x,
                                                         const short* __restrict__ Wt,
                                                         short* __restrict__ h0b) {
    __shared__ short As[64 * 32];    // 4 KB  [m][k]
    __shared__ short Bs[256 * 32];   // 16 KB [n][k]
    const int tid  = threadIdx.x;
    const int wave = tid >> 6, lane = tid & 63;
    const int mlo  = lane & 15, q = lane >> 4;
    const int m0   = blockIdx.x * 64;

    const int ar  = tid >> 2;          // staging row 0..63
    const int acg = (tid & 3) * 8;     // staging col group
    int arow = m0 + ar; if (arow >= N_NODES) arow = N_NODES - 1;   // clamp tail reads
    const float* aptr = x + (size_t)arow * NFEAT + acg;

    floatx4 acc[4][4] = {};   // [mtile][ntile]

    for (int kc = 0; kc < NFEAT; kc += 32) {
        // stage A: 8 fp32 -> 8 bf16 -> one 16B LDS write (wave-contiguous: byte t*16)
        float4 a0 = *(const float4*)(aptr + kc);
        float4 a1 = *(const float4*)(aptr + kc + 4);
        short8 ap;
        ap[0]=f2bf(a0.x); ap[1]=f2bf(a0.y); ap[2]=f2bf(a0.z); ap[3]=f2bf(a0.w);
        ap[4]=f2bf(a1.x); ap[5]=f2bf(a1.y); ap[6]=f2bf(a1.z); ap[7]=f2bf(a1.w);
        *(short8*)&As[ar * 32 + acg] = ap;
        // stage B: 256x32 bf16 (16KB), granule g covers Bs row g>>2, seg (g&3)*8
        #pragma unroll
        for (int it = 0; it < 4; ++it) {
            int g = it * 256 + tid;
            *(short8*)&Bs[g * 8] =
                *(const short8*)(Wt + (size_t)(g >> 2) * NFEAT + kc + (g & 3) * 8);
        }
        __syncthreads();

        short8 af[4], bfr[4];
        #pragma unroll
        for (int t = 0; t < 4; ++t)
            af[t] = *(const short8*)&As[(t * 16 + mlo) * 32 + q * 8];
        #pragma unroll
        for (int u = 0; u < 4; ++u)
            bfr[u] = *(const short8*)&Bs[(wave * 64 + u * 16 + mlo) * 32 + q * 8];
        #pragma unroll
        for (int t = 0; t < 4; ++t)
            #pragma unroll
            for (int u = 0; u < 4; ++u)
                acc[t][u] = __builtin_amdgcn_mfma_f32_16x16x32_bf16(af[t], bfr[u], acc[t][u], 0, 0, 0);
        __syncthreads();
    }

    #pragma unroll
    for (int t = 0; t < 4; ++t) {
        #pragma unroll
        for (int r = 0; r < 4; ++r) {
            int row = m0 + t * 16 + q * 4 + r;
            if (row < N_NODES) {
                #pragma unroll
                for (int u = 0; u < 4; ++u)
                    h0b[(size_t)row * NHID + wave * 64 + u * 16 + mlo] = f2bf(acc[t][u][r]);
            }
        }
    }
}

// ---------------- CSR build: histogram -> scan -> scatter ----------------
__global__ __launch_bounds__(256) void hist_kernel(const int* __restrict__ dst,
                                                   int* __restrict__ deg) {
    int e = blockIdx.x * 256 + threadIdx.x;
    if (e < N_EDGES) atomicAdd(&deg[dst[e]], 1);
}

__global__ __launch_bounds__(256) void scan_partial_kernel(const int* __restrict__ deg,
                                                           int* __restrict__ partial) {
    __shared__ int s[256];
    int i = blockIdx.x * 256 + threadIdx.x;
    int t = threadIdx.x;
    s[t] = (i < N_NODES) ? deg[i] : 0;
    __syncthreads();
    for (int off = 128; off > 0; off >>= 1) {
        if (t < off) s[t] += s[t + off];
        __syncthreads();
    }
    if (t == 0) partial[blockIdx.x] = s[0];
}

__global__ __launch_bounds__(256) void scan_top_kernel(int* __restrict__ partial) {
    __shared__ int s[256];
    int t = threadIdx.x;
    int v = (t < NODE_BLOCKS) ? partial[t] : 0;
    s[t] = v;
    __syncthreads();
    for (int off = 1; off < 256; off <<= 1) {
        int a = (t >= off) ? s[t - off] : 0;
        __syncthreads();
        s[t] += a;
        __syncthreads();
    }
    if (t < NODE_BLOCKS) partial[t] = s[t] - v;   // exclusive
}

__global__ __launch_bounds__(256) void scan_final_kernel(const int* __restrict__ deg,
                                                         const int* __restrict__ partial,
                                                         int* __restrict__ base,
                                                         int* __restrict__ cursor) {
    __shared__ int s[256];
    int i = blockIdx.x * 256 + threadIdx.x;
    int t = threadIdx.x;
    int v = (i < N_NODES) ? deg[i] : 0;
    s[t] = v;
    __syncthreads();
    for (int off = 1; off < 256; off <<= 1) {
        int a = (t >= off) ? s[t - off] : 0;
        __syncthreads();
        s[t] += a;
        __syncthreads();
    }
    int excl = s[t] - v + partial[blockIdx.x];
    if (i < N_NODES) { base[i] = excl; cursor[i] = excl; }
}

// single int2 (src, w-bits) per edge -> one 8B scatter write instead of two 4B
__global__ __launch_bounds__(256) void scatter_kernel(const int* __restrict__ src,
                                                      const int* __restrict__ dst,
                                                      const float* __restrict__ w,
                                                      int* __restrict__ cursor,
                                                      int2* __restrict__ edge_s) {
    int e = blockIdx.x * 256 + threadIdx.x;
    if (e < N_EDGES) {
        int p = atomicAdd(&cursor[dst[e]], 1);
        edge_s[p] = make_int2(src[e], __float_as_int(w[e]));
    }
}

// ---------------- SpMM1 pull (bf16 gather, d=256): agg0[i] = sum w * h0b[src] --------
// One wave per node (4/block); lane covers 4 features (8B load). 1-ahead prefetch.
__global__ __launch_bounds__(256) void spmm1_pull_kernel(const int* __restrict__ base,
                                                         const int* __restrict__ deg,
                                                         const int2* __restrict__ edge_s,
                                                         const short* __restrict__ h0b,
                                                         float* __restrict__ agg0) {
    const int node = blockIdx.x * 4 + (threadIdx.x >> 6);
    const int lane = threadIdx.x & 63;
    const int start = base[node];
    const int len   = deg[node];
    float4 acc = {0.f, 0.f, 0.f, 0.f};

    int2 e = {0, 0};
    short4v hv = {0, 0, 0, 0};
    if (len > 0) {
        e  = edge_s[start];
        hv = *(const short4v*)(h0b + (size_t)e.y * 0 + (size_t)e.x * NHID + lane * 4);
    }
    for (int j = 0; j < len; ++j) {
        float wt = __int_as_float(e.y);
        float v0 = bf2f(hv[0]), v1 = bf2f(hv[1]), v2 = bf2f(hv[2]), v3 = bf2f(hv[3]);
        int2 en = e; short4v hn = hv;
        if (j + 1 < len) {
            en = edge_s[start + j + 1];
            hn = *(const short4v*)(h0b + (size_t)en.x * NHID + lane * 4);
        }
        acc.x += wt * v0; acc.y += wt * v1; acc.z += wt * v2; acc.w += wt * v3;
        e = en; hv = hn;
    }
    ((float4*)agg0)[(size_t)node * 64 + lane] = acc;
}

// ---------------- GEMM2 (MFMA): h2 = relu(agg0 + b1) @ W2, bf16 out ------------------
// Tile 64(M) x 64(N=full); W2^T fully LDS-resident (padded to kill conflicts);
// relu+bias+cast fused into A-staging. K=256 -> 8 chunks of 32.
__global__ __launch_bounds__(256) void gemm2_mfma_kernel(const float* __restrict__ agg0,
                                                         const float* __restrict__ b1,
                                                         const short* __restrict__ W2t,
                                                         short* __restrict__ h2b) {
    __shared__ short Bs[64 * 264];   // 33 KB, [n][k] pad +8
    __shared__ short As[64 * 32];    // 4 KB
    const int tid  = threadIdx.x;
    const int wave = tid >> 6, lane = tid & 63;
    const int mlo  = lane & 15, q = lane >> 4;
    const int m0   = blockIdx.x * 64;

    {   // stage full W2t [64x256] once
        int n = tid >> 2, seg = (tid & 3) * 64;
        #pragma unroll
        for (int i = 0; i < 8; ++i)
            *(short8*)&Bs[n * 264 + seg + i * 8] =
                *(const short8*)(W2t + n * NHID + seg + i * 8);
    }

    const int ar  = tid >> 2;
    const int acg = (tid & 3) * 8;
    int arow = m0 + ar; if (arow >= N_NODES) arow = N_NODES - 1;
    const float* aptr = agg0 + (size_t)arow * NHID + acg;

    floatx4 acc[4] = {};   // [ntile]

    for (int kc = 0; kc < NHID; kc += 32) {
        float4 a0 = *(const float4*)(aptr + kc);
        float4 a1 = *(const float4*)(aptr + kc + 4);
        float4 c0 = *(const float4*)(b1 + kc + acg);
        float4 c1 = *(const float4*)(b1 + kc + acg + 4);
        float v0 = a0.x + c0.x, v1 = a0.y + c0.y, v2 = a0.z + c0.z, v3 = a0.w + c0.w;
        float v4 = a1.x + c1.x, v5 = a1.y + c1.y, v6 = a1.z + c1.z, v7 = a1.w + c1.w;
        short8 ap;
        ap[0] = f2bf(v0 > 0.f ? v0 : 0.f); ap[1] = f2bf(v1 > 0.f ? v1 : 0.f);
        ap[2] = f2bf(v2 > 0.f ? v2 : 0.f); ap[3] = f2bf(v3 > 0.f ? v3 : 0.f);
        ap[4] = f2bf(v4 > 0.f ? v4 : 0.f); ap[5] = f2bf(v5 > 0.f ? v5 : 0.f);
        ap[6] = f2bf(v6 > 0.f ? v6 : 0.f); ap[7] = f2bf(v7 > 0.f ? v7 : 0.f);
        *(short8*)&As[ar * 32 + acg] = ap;
        __syncthreads();

        short8 af = *(const short8*)&As[(wave * 16 + mlo) * 32 + q * 8];
        #pragma unroll
        for (int u = 0; u < 4; ++u) {
            short8 bfr = *(const short8*)&Bs[(u * 16 + mlo) * 264 + kc + q * 8];
            acc[u] = __builtin_amdgcn_mfma_f32_16x16x32_bf16(af, bfr, acc[u], 0, 0, 0);
        }
        __syncthreads();
    }

    #pragma unroll
    for (int r = 0; r < 4; ++r) {
        int row = m0 + wave * 16 + q * 4 + r;
        if (row < N_NODES) {
            #pragma unroll
            for (int u = 0; u < 4; ++u)
                h2b[(size_t)row * NCLASS + u * 16 + mlo] = f2bf(acc[u][r]);
        }
    }
}

// ---------------- SpMM2 pull (bf16 gather, d=64) ----------------
// One wave per node; half=lane>>5 processes edges of that parity (2 edges in flight),
// lane covers 2 features via bf16x2; halves combined by shfl_xor(32).
__global__ __launch_bounds__(256) void spmm2_pull_kernel(const int* __restrict__ base,
                                                         const int* __restrict__ deg,
                                                         const int2* __restrict__ edge_s,
                                                         const short* __restrict__ h2b,
                                                         float* __restrict__ agg1) {
    const int node = blockIdx.x * 4 + (threadIdx.x >> 6);
    const int lane = threadIdx.x & 63;
    const int half = lane >> 5;
    const int c    = lane & 31;
    const int start = base[node];
    const int len   = deg[node];

    float a0 = 0.f, a1 = 0.f;
    int j = half;
    int2 e = {0, 0};
    short2v hv = {0, 0};
    if (j < len) {
        e  = edge_s[start + j];
        hv = *(const short2v*)(h2b + (size_t)e.x * NCLASS + c * 2);
    }
    while (j < len) {
        float wt = __int_as_float(e.y);
        float v0 = bf2f(hv[0]), v1 = bf2f(hv[1]);
        int jn = j + 2;
        int2 en = e; short2v hn = hv;
        if (jn < len) {
            en = edge_s[start + jn];
            hn = *(const short2v*)(h2b + (size_t)en.x * NCLASS + c * 2);
        }
        a0 += wt * v0; a1 += wt * v1;
        e = en; hv = hn; j = jn;
    }
    a0 += __shfl_xor(a0, 32);
    a1 += __shfl_xor(a1, 32);
    if (half == 0) {
        float2 o = {a0, a1};
        *(float2*)(agg1 + (size_t)node * NCLASS + c * 2) = o;
    }
}

// ---------------- log_softmax over 64 classes, + b2 ----------------
__global__ __launch_bounds__(256) void logsoftmax_kernel(const float* __restrict__ agg1,
                                                         const float* __restrict__ b2,
                                                         float* __restrict__ out) {
    const int lane = threadIdx.x & 63;
    const int row  = blockIdx.x * 4 + (threadIdx.x >> 6);
    float v = agg1[(size_t)row * NCLASS + lane] + b2[lane];

    float m = v;
    #pragma unroll
    for (int off = 32; off > 0; off >>= 1) m = fmaxf(m, __shfl_xor(m, off, 64));
    float ex = expf(v - m);
    float s = ex;
    #pragma unroll
    for (int off = 32; off > 0; off >>= 1) s += __shfl_xor(s, off, 64);

    out[(size_t)row * NCLASS + lane] = v - m - logf(s);
}

extern "C" void kernel_launch(void* const* d_in, const int* in_sizes, int n_in,
                              void* d_out, int out_size, void* d_ws, size_t ws_size,
                              hipStream_t stream) {
    const float* x   = (const float*)d_in[0];
    const int*   es0 = (const int*)  d_in[1];
    const int*   ed0 = (const int*)  d_in[2];
    const float* ew0 = (const float*)d_in[3];
    const int*   es1 = (const int*)  d_in[4];
    const int*   ed1 = (const int*)  d_in[5];
    const float* ew1 = (const float*)d_in[6];
    const float* W1  = (const float*)d_in[7];
    const float* b1  = (const float*)d_in[8];
    const float* W2  = (const float*)d_in[9];
    const float* b2  = (const float*)d_in[10];
    float* out = (float*)d_out;

    // ws layout (102.4 MB):
    //   A [0, 51.2MB):  h0b bf16 [50000x256] = 25.6MB at [0,25.6);
    //                   after spmm1: h2b bf16 [0,6.4) + agg1 fp32 [6.4,19.2)
    //   B [51.2,102.4): agg0 fp32 [50000x256] (written by spmm1)
    char* ws = (char*)d_ws;
    const size_t SZ_A = (size_t)N_NODES * NHID * sizeof(float);   // 51.2 MB
    short* h0b  = (short*)ws;
    float* agg0 = (float*)(ws + SZ_A);
    short* h2b  = (short*)ws;
    float* agg1 = (float*)(ws + (size_t)N_NODES * NCLASS * sizeof(short));  // 6.4MB off

    // d_out scratch (12.8 MB; fully overwritten by logsoftmax):
    //   [0, 6.7MB): CSR (deg/base/cursor/partial/edge_s int2)
    //   [8MiB, 8.5MiB): Wt bf16;  [9MiB, +32KB): W2t bf16
    int*   deg     = (int*)d_out;
    int*   basep   = deg + N_NODES;
    int*   cursor  = basep + N_NODES;
    int*   partial = cursor + N_NODES;
    int2*  edge_s  = (int2*)(partial + 1024);          // byte off 604,096 (8B aligned)
    short* Wt      = (short*)((char*)d_out + (8u << 20));
    short* W2t     = (short*)((char*)d_out + (9u << 20));

    // ---- build CSR for layer-1 edges (by dst) ----
    hipMemsetAsync(deg, 0, N_NODES * sizeof(int), stream);
    hist_kernel<<<EDGE_BLOCKS, 256, 0, stream>>>(ed0, deg);
    scan_partial_kernel<<<NODE_BLOCKS, 256, 0, stream>>>(deg, partial);
    scan_top_kernel<<<1, 256, 0, stream>>>(partial);
    scan_final_kernel<<<NODE_BLOCKS, 256, 0, stream>>>(deg, partial, basep, cursor);
    scatter_kernel<<<EDGE_BLOCKS, 256, 0, stream>>>(es0, ed0, ew0, cursor, edge_s);

    // ---- layer 1: GEMM (fused cast) + pull-SpMM ----
    cast_w1t_kernel<<<NFEAT, 256, 0, stream>>>(W1, Wt);
    cast_w2t_kernel<<<NCLASS, 256, 0, stream>>>(W2, W2t);
    gemm1_mfma_kernel<<<MTILES, 256, 0, stream>>>(x, Wt, h0b);
    spmm1_pull_kernel<<<N_NODES / 4, 256, 0, stream>>>(basep, deg, edge_s, h0b, agg0);

    // ---- build CSR for layer-2 edges (reuse scratch; stream-ordered after spmm1) ----
    hipMemsetAsync(deg, 0, N_NODES * sizeof(int), stream);
    hist_kernel<<<EDGE_BLOCKS, 256, 0, stream>>>(ed1, deg);
    scan_partial_kernel<<<NODE_BLOCKS, 256, 0, stream>>>(deg, partial);
    scan_top_kernel<<<1, 256, 0, stream>>>(partial);
    scan_final_kernel<<<NODE_BLOCKS, 256, 0, stream>>>(deg, partial, basep, cursor);
    scatter_kernel<<<EDGE_BLOCKS, 256, 0, stream>>>(es1, ed1, ew1, cursor, edge_s);

    // ---- layer 2: GEMM (fused relu+bias+cast) + pull-SpMM + log_softmax ----
    gemm2_mfma_kernel<<<MTILES, 256, 0, stream>>>(agg0, b1, W2t, h2b);
    spmm2_pull_kernel<<<N_NODES / 4, 256, 0, stream>>>(basep, deg, edge_s, h2b, agg1);
    logsoftmax_kernel<<<N_NODES / 4, 256, 0, stream>>>(agg1, b2, out);
}